// Round 7
// baseline (306.033 us; speedup 1.0000x reference)
//
#include <hip/hip_runtime.h>
#include <cstdint>
#include <cstddef>
#include <cfloat>

// Problem constants (match reference)
static constexpr int BATCH = 32;
static constexpr int KJ    = 17;   // heat channels (joints)
static constexpr int LL    = 19;   // limbs
static constexpr int HH    = 160;
static constexpr int WW    = 160;
static constexpr int PPK   = 30;   // top-k peaks
static constexpr int SS    = 10;   // samples along limb
static constexpr int HW    = HH * WW;
static constexpr int CGW   = WW / 4;        // 40 float4 cells per row
static constexpr int CAP   = 4096;          // full candidate capacity (fallback)
static constexpr int HICAP = 512;           // hi-list capacity (v > HITHR)
static constexpr int NPAIR = PPK * PPK;     // 900
static constexpr int HALFP = NPAIR / 2;     // 450 active threads in conn
#define HITHR 0.98f

// conn quarter-plane staging
static constexpr int QROWS = 40;            // quarter-plane rows
static constexpr int QCNT  = QROWS * WW;    // 6400 floats = 25.6 KB
static constexpr int QF4   = QCNT / 4;      // 1600 float4

__constant__ int d_ska[LL] = {15,13,16,14,11,5,6,5,5,6,7,8,1,0,0,1,2,3,4};
__constant__ int d_skb[LL] = {13,11,14,12,12,11,12,6,7,8,9,10,2,1,2,3,4,5,6};
// t = linspace(0,1,10) in f32 (verified identical to f32(s/9.0))
__constant__ float d_ts[SS] = {
    0.0f,
    (float)(1.0/9.0), (float)(2.0/9.0), (float)(3.0/9.0),
    (float)(4.0/9.0), (float)(5.0/9.0), (float)(6.0/9.0),
    (float)(7.0/9.0), (float)(8.0/9.0),
    1.0f
};

__device__ __forceinline__ float max3f(float a, float b, float c) {
    return fmaxf(fmaxf(a, b), c);
}
__device__ __forceinline__ unsigned long long umax64(unsigned long long a, unsigned long long b) {
    return a > b ? a : b;
}
// async global->LDS DMA: 64 lanes x 16B, lds base wave-uniform, lane i -> base + i*16
__device__ __forceinline__ void async_copy16(const float4* gsrc_lane, float4* lds_wave_base) {
    __builtin_amdgcn_global_load_lds(
        (const __attribute__((address_space(1))) void*)gsrc_lane,
        (__attribute__((address_space(3))) void*)lds_wave_base,
        16, 0, 0);
}

// ---------------------------------------------------------------------------
// Kernel 1: per-channel peak detection + top-30 + subpixel refine.
// 1024 threads per (b,k) channel.
// HOT PASS: load only the center float4; lanes with any element > 0.98 load
// the 8 neighbor words (masked lanes issue no memory requests) and test
// local-max; ballot-append survivors to the hi-list. If 30 <= hcnt <= 512
// the global top-30 is provably inside the hi-list (all non-hi candidates
// <= 0.98 < every hi value) -> wave 0 selects it alone.
// FALLBACK (rare): full rescan with the validated >0.1 machinery.
// ---------------------------------------------------------------------------
__global__ __launch_bounds__(1024, 2) void peaks_kernel(const float* __restrict__ heat,
                                                        float* __restrict__ out)
{
    const int ch = blockIdx.x;              // b*17 + k
    const float* hp = heat + (size_t)ch * HW;

    __shared__ unsigned long long keys[CAP];
    __shared__ unsigned long long hikeys[HICAP];
    __shared__ unsigned long long sel16[16 * PPK];
    __shared__ unsigned long long sel[PPK];
    __shared__ int cnt;
    __shared__ int hcnt;

    const int tid  = threadIdx.x;
    const int lane = tid & 63;
    const int wave = tid >> 6;
    const unsigned long long ltmask = ((unsigned long long)1 << lane) - 1ull;

    if (tid == 0) { cnt = 0; hcnt = 0; }
    __syncthreads();

    // ---- HOT scan: center-only load, neighbors only for hi lanes ----
    for (int c = tid; c < HW / 4; c += 1024) {
        int y  = c / CGW;
        int cg = c - y * CGW;
        int x0 = cg * 4;
        const float* rc = hp + y * WW + x0;
        float4 vc = *(const float4*)rc;

        bool h_any = (vc.x > HITHR) || (vc.y > HITHR) || (vc.z > HITHR) || (vc.w > HITHR);
        if (!__any(h_any ? 1 : 0)) continue;   // wave-uniform skip (rare)

        bool h0 = false, h1 = false, h2 = false, h3 = false;
        if (h_any) {
            int yu = (y > 0) ? y - 1 : 0;
            int yd = (y < HH - 1) ? y + 1 : HH - 1;
            const float* ru = hp + yu * WW + x0;
            const float* rd = hp + yd * WW + x0;
            float4 vu = *(const float4*)ru;
            float4 vd = *(const float4*)rd;
            int offL = (x0 > 0) ? -1 : 0;
            int offR = (x0 + 4 < WW) ? 4 : 3;
            float lc  = rc[offL], lu  = ru[offL], ld  = rd[offL];
            float rcx = rc[offR], rux = ru[offR], rdx = rd[offR];

            float mu0 = max3f(lu, vu.x, vu.y), mu1 = max3f(vu.x, vu.y, vu.z);
            float mu2 = max3f(vu.y, vu.z, vu.w), mu3 = max3f(vu.z, vu.w, rux);
            float mc0 = max3f(lc, vc.x, vc.y), mc1 = max3f(vc.x, vc.y, vc.z);
            float mc2 = max3f(vc.y, vc.z, vc.w), mc3 = max3f(vc.z, vc.w, rcx);
            float md0 = max3f(ld, vd.x, vd.y), md1 = max3f(vd.x, vd.y, vd.z);
            float md2 = max3f(vd.y, vd.z, vd.w), md3 = max3f(vd.z, vd.w, rdx);

            float nm0 = max3f(mu0, mc0, md0);
            float nm1 = max3f(mu1, mc1, md1);
            float nm2 = max3f(mu2, mc2, md2);
            float nm3 = max3f(mu3, mc3, md3);

            h0 = (vc.x == nm0) && (vc.x > HITHR);
            h1 = (vc.y == nm1) && (vc.y > HITHR);
            h2 = (vc.z == nm2) && (vc.z > HITHR);
            h3 = (vc.w == nm3) && (vc.w > HITHR);
        }
        // all lanes uniformly active here
        unsigned long long b0 = __ballot(h0);
        unsigned long long b1 = __ballot(h1);
        unsigned long long b2 = __ballot(h2);
        unsigned long long b3 = __ballot(h3);
        int c0 = __popcll(b0), c1 = __popcll(b1), c2 = __popcll(b2), c3 = __popcll(b3);
        int tot = c0 + c1 + c2 + c3;
        if (tot == 0) continue;
        int base = 0;
        if (lane == 0) base = atomicAdd(&hcnt, tot);
        base = __shfl(base, 0);

        int idx0 = y * WW + x0;
        if (h0) { int s = base + __popcll(b0 & ltmask); if (s < HICAP)
            hikeys[s] = ((unsigned long long)__float_as_uint(vc.x) << 32) | (unsigned long long)(0xFFFFFFFFu - (unsigned)(idx0 + 0)); }
        if (h1) { int s = base + c0 + __popcll(b1 & ltmask); if (s < HICAP)
            hikeys[s] = ((unsigned long long)__float_as_uint(vc.y) << 32) | (unsigned long long)(0xFFFFFFFFu - (unsigned)(idx0 + 1)); }
        if (h2) { int s = base + c0 + c1 + __popcll(b2 & ltmask); if (s < HICAP)
            hikeys[s] = ((unsigned long long)__float_as_uint(vc.z) << 32) | (unsigned long long)(0xFFFFFFFFu - (unsigned)(idx0 + 2)); }
        if (h3) { int s = base + c0 + c1 + c2 + __popcll(b3 & ltmask); if (s < HICAP)
            hikeys[s] = ((unsigned long long)__float_as_uint(vc.w) << 32) | (unsigned long long)(0xFFFFFFFFu - (unsigned)(idx0 + 3)); }
    }
    __syncthreads();

    const int hn = hcnt;
    if (hn >= PPK && hn <= HICAP) {
        // ---- FAST PATH: wave 0 selects top-30 from <=512 hi keys ----
        if (wave == 0) {
            unsigned long long k[8];
            #pragma unroll
            for (int i = 0; i < 8; ++i) {
                int p = lane + i * 64;
                k[i] = (p < hn) ? hikeys[p] : 0ull;
            }
            for (int r = 0; r < PPK; ++r) {
                unsigned long long best = 0ull;
                #pragma unroll
                for (int i = 0; i < 8; ++i) best = umax64(best, k[i]);
                #pragma unroll
                for (int off = 1; off < 64; off <<= 1)
                    best = umax64(best, (unsigned long long)__shfl_xor((long long)best, off));
                if (best != 0ull) {
                    #pragma unroll
                    for (int i = 0; i < 8; ++i)
                        if (k[i] == best) k[i] = 0ull;     // keys unique when nonzero
                }
                if (lane == 0) sel[r] = best;
            }
        }
    } else {
        // ---- FALLBACK: full rescan with >0.1 candidates (validated path) ----
        for (int c = tid; c < HW / 4; c += 1024) {
            int y  = c / CGW;
            int cg = c - y * CGW;
            int x0 = cg * 4;
            int yu = (y > 0) ? y - 1 : 0;
            int yd = (y < HH - 1) ? y + 1 : HH - 1;
            const float* rc = hp + y  * WW + x0;
            const float* ru = hp + yu * WW + x0;
            const float* rd = hp + yd * WW + x0;
            float4 vc = *(const float4*)rc;
            float4 vu = *(const float4*)ru;
            float4 vd = *(const float4*)rd;
            int offL = (x0 > 0) ? -1 : 0;
            int offR = (x0 + 4 < WW) ? 4 : 3;
            float lc  = rc[offL], lu  = ru[offL], ld  = rd[offL];
            float rcx = rc[offR], rux = ru[offR], rdx = rd[offR];

            float mu0 = max3f(lu, vu.x, vu.y), mu1 = max3f(vu.x, vu.y, vu.z);
            float mu2 = max3f(vu.y, vu.z, vu.w), mu3 = max3f(vu.z, vu.w, rux);
            float mc0 = max3f(lc, vc.x, vc.y), mc1 = max3f(vc.x, vc.y, vc.z);
            float mc2 = max3f(vc.y, vc.z, vc.w), mc3 = max3f(vc.z, vc.w, rcx);
            float md0 = max3f(ld, vd.x, vd.y), md1 = max3f(vd.x, vd.y, vd.z);
            float md2 = max3f(vd.y, vd.z, vd.w), md3 = max3f(vd.z, vd.w, rdx);

            float nm0 = max3f(mu0, mc0, md0);
            float nm1 = max3f(mu1, mc1, md1);
            float nm2 = max3f(mu2, mc2, md2);
            float nm3 = max3f(mu3, mc3, md3);

            bool pk0 = (vc.x == nm0) && (vc.x > 0.1f);
            bool pk1 = (vc.y == nm1) && (vc.y > 0.1f);
            bool pk2 = (vc.z == nm2) && (vc.z > 0.1f);
            bool pk3 = (vc.w == nm3) && (vc.w > 0.1f);

            unsigned long long b0 = __ballot(pk0);
            unsigned long long b1 = __ballot(pk1);
            unsigned long long b2 = __ballot(pk2);
            unsigned long long b3 = __ballot(pk3);
            int c0 = __popcll(b0), c1 = __popcll(b1), c2 = __popcll(b2), c3 = __popcll(b3);
            int tot = c0 + c1 + c2 + c3;
            int base = 0;
            if (lane == 0 && tot > 0) base = atomicAdd(&cnt, tot);
            base = __shfl(base, 0);

            int idx0 = y * WW + x0;
            if (pk0) { int s = base + __popcll(b0 & ltmask); if (s < CAP)
                keys[s] = ((unsigned long long)__float_as_uint(vc.x) << 32) | (unsigned long long)(0xFFFFFFFFu - (unsigned)(idx0 + 0)); }
            if (pk1) { int s = base + c0 + __popcll(b1 & ltmask); if (s < CAP)
                keys[s] = ((unsigned long long)__float_as_uint(vc.y) << 32) | (unsigned long long)(0xFFFFFFFFu - (unsigned)(idx0 + 1)); }
            if (pk2) { int s = base + c0 + c1 + __popcll(b2 & ltmask); if (s < CAP)
                keys[s] = ((unsigned long long)__float_as_uint(vc.z) << 32) | (unsigned long long)(0xFFFFFFFFu - (unsigned)(idx0 + 2)); }
            if (pk3) { int s = base + c0 + c1 + c2 + __popcll(b3 & ltmask); if (s < CAP)
                keys[s] = ((unsigned long long)__float_as_uint(vc.w) << 32) | (unsigned long long)(0xFFFFFFFFu - (unsigned)(idx0 + 3)); }
        }
        __syncthreads();

        const int n = (cnt < CAP) ? cnt : CAP;
        unsigned long long k[4];
        {
            int base0 = wave * 256 + lane;
            #pragma unroll
            for (int i = 0; i < 4; ++i) {
                int p = base0 + i * 64;
                k[i] = (p < n) ? keys[p] : 0ull;
            }
        }
        for (int r = 0; r < PPK; ++r) {
            unsigned long long best = umax64(umax64(k[0], k[1]), umax64(k[2], k[3]));
            #pragma unroll
            for (int off = 1; off < 64; off <<= 1)
                best = umax64(best, (unsigned long long)__shfl_xor((long long)best, off));
            if (best != 0ull) {
                #pragma unroll
                for (int i = 0; i < 4; ++i)
                    if (k[i] == best) k[i] = 0ull;
            }
            if (lane == 0) sel16[wave * PPK + r] = best;
        }
        __syncthreads();
        if (wave == 0) {
            unsigned long long m[8];
            #pragma unroll
            for (int i = 0; i < 8; ++i) {
                int p = lane + i * 64;
                m[i] = (p < 16 * PPK) ? sel16[p] : 0ull;
            }
            for (int r = 0; r < PPK; ++r) {
                unsigned long long best = 0ull;
                #pragma unroll
                for (int i = 0; i < 8; ++i) best = umax64(best, m[i]);
                #pragma unroll
                for (int off = 1; off < 64; off <<= 1)
                    best = umax64(best, (unsigned long long)__shfl_xor((long long)best, off));
                if (best != 0ull) {
                    #pragma unroll
                    for (int i = 0; i < 8; ++i)
                        if (m[i] == best) m[i] = 0ull;
                }
                if (lane == 0) sel[r] = best;
            }
        }
    }
    __syncthreads();

    // ---- emit peaks with subpixel refinement (bit-identical to validated) ----
    if (tid < PPK) {
        unsigned long long g = sel[tid];
        float px = 0.0f, py = 0.0f, sc = 0.0f;
        if (g != 0ull) {
            float v = __uint_as_float((unsigned int)(g >> 32));
            int idx = (int)(0xFFFFFFFFu - (unsigned int)(g & 0xFFFFFFFFull));
            int y = idx / WW;
            int x = idx - y * WW;
            float dx = 0.0f, dy = 0.0f;
            if (x > 0 && x < WW - 1 && y > 0 && y < HH - 1) {
                float r_ = hp[y * WW + x + 1];
                float l_ = hp[y * WW + x - 1];
                float dn = hp[(y + 1) * WW + x];
                float up = hp[(y - 1) * WW + x];
                float dx_raw = 0.5f * (r_ - l_);
                float dy_raw = 0.5f * (dn - up);
                float dxx = __fsub_rn(__fadd_rn(r_, l_), 2.0f * v);
                float dyy = __fsub_rn(__fadd_rn(dn, up), 2.0f * v);
                dx = (fabsf(dxx) > 1e-6f) ? (dx_raw / (-dxx)) : dx_raw;
                dy = (fabsf(dyy) > 1e-6f) ? (dy_raw / (-dyy)) : dy_raw;
            }
            px = __fadd_rn((float)x, dx);
            py = __fadd_rn((float)y, dy);
            sc = v;
        }
        float* o = out + ((size_t)ch * PPK + tid) * 3;
        o[0] = px;
        o[1] = py;
        o[2] = sc;
    }
}

// ---------------------------------------------------------------------------
// Kernel 2: PAF connection scoring — UNCHANGED from validated round 5.
// Double-buffered quarter-plane pipeline with async global->LDS DMA.
// ---------------------------------------------------------------------------
__global__ __launch_bounds__(512, 4) void conn_kernel(const float* __restrict__ paf,
                                                      const float* __restrict__ peaks,
                                                      float* __restrict__ conn)
{
    const int bl = blockIdx.x;        // b*19 + l
    const int b  = bl / LL;
    const int l  = bl - b * LL;

    __shared__ float buf[2][QCNT];    // 2 x 25.6 KB
    __shared__ float As[PPK * 3];
    __shared__ float Bs[PPK * 3];

    const int tid  = threadIdx.x;
    const int lane = tid & 63;
    const int wave = tid >> 6;
    {
        const float* pa = peaks + (((size_t)b * KJ) + d_ska[l]) * (PPK * 3);
        const float* pb = peaks + (((size_t)b * KJ) + d_skb[l]) * (PPK * 3);
        if (tid < PPK * 3)            As[tid] = pa[tid];
        else if (tid < 2 * PPK * 3)   Bs[tid - PPK * 3] = pb[tid - PPK * 3];
    }

    const float*  src  = paf + (((size_t)b * (2 * LL)) + 2 * l) * HW;  // pafx; pafy = +HW
    const float4* src4 = (const float4*)src;

    // ---- kick off DMA of quarter 0 (pafx rows 0-39) into buf[0] ----
    {
        float4* b4 = (float4*)buf[0];
        #pragma unroll
        for (int c = 0; c < 3; ++c)
            async_copy16(src4 + c * 512 + tid, b4 + c * 512 + wave * 64);
        if (wave == 0)
            async_copy16(src4 + 1536 + lane, b4 + 1536);
    }
    __syncthreads();   // drains DMA (vmcnt(0) before barrier) + As/Bs stores

    // ---- per-pair precompute; everything constant-indexed -> registers ----
    const bool active = (tid < HALFP);
    const int p0 = active ? tid : (NPAIR - 1);
    const int p1 = active ? (tid + HALFP) : (NPAIR - 1);

    int   lin[2][SS];
    float accv[2][SS];
    float vxp[2], vyp[2], sap[2], sbp[2];

    #pragma unroll
    for (int q = 0; q < 2; ++q) {
        int p = (q == 0) ? p0 : p1;
        int i = p / PPK;
        int j = p - i * PPK;
        float ax = As[i * 3 + 0], ay = As[i * 3 + 1], sa = As[i * 3 + 2];
        float bx = Bs[j * 3 + 0], by = Bs[j * 3 + 1], sb = Bs[j * 3 + 2];
        float dxl = __fsub_rn(bx, ax);
        float dyl = __fsub_rn(by, ay);
        float nsq = __fadd_rn(__fmul_rn(dxl, dxl), __fmul_rn(dyl, dyl));
        float nrm = __fadd_rn(sqrtf(nsq), 1e-8f);
        vxp[q] = dxl / nrm;
        vyp[q] = dyl / nrm;
        sap[q] = sa;
        sbp[q] = sb;
        #pragma unroll
        for (int s = 0; s < SS; ++s) {
            float t  = d_ts[s];
            float xs = __fadd_rn(ax, __fmul_rn(t, dxl));
            float ys = __fadd_rn(ay, __fmul_rn(t, dyl));
            float rx = rintf(xs);               // round half to even, matches jnp.round
            float ry = rintf(ys);
            rx = fminf(fmaxf(rx, 0.0f), (float)(WW - 1));
            ry = fminf(fmaxf(ry, 0.0f), (float)(HH - 1));
            lin[q][s] = (int)ry * WW + (int)rx;  // in [0, HW)
        }
    }

    // ---- 8-quarter pipeline: DMA next while gathering current ----
    for (int qq = 0; qq < 8; ++qq) {
        const int cur = qq & 1;
        if (qq < 7) {
            const int nq = qq + 1;
            const float4* s4 = (const float4*)(src + (size_t)(nq >> 2) * HW + (nq & 3) * QCNT);
            float4* b4 = (float4*)buf[1 - cur];
            #pragma unroll
            for (int c = 0; c < 3; ++c)
                async_copy16(s4 + c * 512 + tid, b4 + c * 512 + wave * 64);
            if (wave == 0)
                async_copy16(s4 + 1536 + lane, b4 + 1536);
        }
        // gather current quarter from LDS (constant-indexed, fully unrolled)
        const int comp = qq >> 2;              // 0 = pafx, 1 = pafy
        const int lo   = (qq & 3) * QCNT;
        #pragma unroll
        for (int q = 0; q < 2; ++q) {
            #pragma unroll
            for (int s = 0; s < SS; ++s) {
                int lrel = lin[q][s] - lo;
                if ((unsigned)lrel < (unsigned)QCNT) {
                    float v = buf[cur][lrel];
                    if (comp == 0) accv[q][s] = __fmul_rn(v, vxp[q]);
                    else           accv[q][s] = __fadd_rn(accv[q][s], __fmul_rn(v, vyp[q]));
                }
            }
        }
        __syncthreads();   // drains gathers of buf[cur] AND the DMA into buf[1-cur]
    }

    // ---- fold + emit ----
    if (active) {
        #pragma unroll
        for (int q = 0; q < 2; ++q) {
            int p = (q == 0) ? p0 : p1;
            int cntc = 0;
            #pragma unroll
            for (int s = 0; s < SS; ++s)
                if (accv[q][s] > 0.05f) ++cntc;
            float s01 = __fadd_rn(accv[q][0], accv[q][1]);
            float s23 = __fadd_rn(accv[q][2], accv[q][3]);
            float s45 = __fadd_rn(accv[q][4], accv[q][5]);
            float s67 = __fadd_rn(accv[q][6], accv[q][7]);
            float sum = __fadd_rn(__fadd_rn(s01, s23), __fadd_rn(s45, s67));
            sum = __fadd_rn(sum, accv[q][8]);
            sum = __fadd_rn(sum, accv[q][9]);
            float mean = sum / 10.0f;
            bool va = sap[q] > 0.1f;
            bool vb = sbp[q] > 0.1f;
            bool cond = (mean > 0.0f) && (cntc >= 9) && va && vb;  // ratio>0.8 <=> cnt>=9
            float val = 0.0f;
            if (cond) val = __fadd_rn(mean, __fmul_rn(0.5f, __fadd_rn(sap[q], sbp[q])));
            conn[(size_t)bl * NPAIR + p] = val;
        }
    }
}

extern "C" void kernel_launch(void* const* d_in, const int* in_sizes, int n_in,
                              void* d_out, int out_size, void* d_ws, size_t ws_size,
                              hipStream_t stream)
{
    const float* heat = (const float*)d_in[0];   // [32,17,160,160]
    const float* paf  = (const float*)d_in[1];   // [32,38,160,160]
    float* out = (float*)d_out;

    float* peaks_out = out;                                   // 32*17*30*3 = 48960
    float* conn_out  = out + (size_t)BATCH * KJ * PPK * 3;    // 32*19*30*30 = 547200

    hipLaunchKernelGGL(peaks_kernel, dim3(BATCH * KJ), dim3(1024), 0, stream,
                       heat, peaks_out);
    hipLaunchKernelGGL(conn_kernel, dim3(BATCH * LL), dim3(512), 0, stream,
                       paf, peaks_out, conn_out);
}

// Round 8
// 286.173 us; speedup vs baseline: 1.0694x; 1.0694x over previous
//
#include <hip/hip_runtime.h>
#include <cstdint>
#include <cstddef>
#include <cfloat>

// Problem constants (match reference)
static constexpr int BATCH = 32;
static constexpr int KJ    = 17;   // heat channels (joints)
static constexpr int LL    = 19;   // limbs
static constexpr int HH    = 160;
static constexpr int WW    = 160;
static constexpr int PPK   = 30;   // top-k peaks
static constexpr int SS    = 10;   // samples along limb
static constexpr int HW    = HH * WW;
static constexpr int CAP   = 3072;          // full candidate capacity (E~2844, +4.5 sigma)
static constexpr int HICAP = 512;           // hi-list capacity (v > HITHR)
static constexpr int NPAIR = PPK * PPK;     // 900
static constexpr int HALFP = NPAIR / 2;     // 450 active threads in conn
#define HITHR 0.98f

// peaks strip staging
static constexpr int NSTRIP = 10;           // strips per channel
static constexpr int SR     = 16;           // center rows per strip
static constexpr int BROWS  = 18;           // buffer rows (16 + 2 halo)
static constexpr int BFLT   = BROWS * WW;   // 2880 floats per buffer

// conn quarter-plane staging
static constexpr int QROWS = 40;            // quarter-plane rows
static constexpr int QCNT  = QROWS * WW;    // 6400 floats = 25.6 KB
static constexpr int QF4   = QCNT / 4;      // 1600 float4

__constant__ int d_ska[LL] = {15,13,16,14,11,5,6,5,5,6,7,8,1,0,0,1,2,3,4};
__constant__ int d_skb[LL] = {13,11,14,12,12,11,12,6,7,8,9,10,2,1,2,3,4,5,6};
// t = linspace(0,1,10) in f32 (verified identical to f32(s/9.0))
__constant__ float d_ts[SS] = {
    0.0f,
    (float)(1.0/9.0), (float)(2.0/9.0), (float)(3.0/9.0),
    (float)(4.0/9.0), (float)(5.0/9.0), (float)(6.0/9.0),
    (float)(7.0/9.0), (float)(8.0/9.0),
    1.0f
};

__device__ __forceinline__ float max3f(float a, float b, float c) {
    return fmaxf(fmaxf(a, b), c);
}
__device__ __forceinline__ unsigned long long umax64(unsigned long long a, unsigned long long b) {
    return a > b ? a : b;
}
// async global->LDS DMA: lane i writes lds base + i*16 (base wave-uniform)
__device__ __forceinline__ void async_copy16(const float4* gsrc_lane, float4* lds_wave_base) {
    __builtin_amdgcn_global_load_lds(
        (const __attribute__((address_space(1))) void*)gsrc_lane,
        (__attribute__((address_space(3))) void*)lds_wave_base,
        16, 0, 0);
}

// ---------------------------------------------------------------------------
// Kernel 1: per-channel peak detection + top-30 + subpixel refine.
// 256 threads (4 waves) per (b,k) channel. Heat is streamed via async DMA
// into double-buffered 18-row LDS strips; the 3x3-max scan reads LDS only
// (conn_kernel proved DMA streams at ~2 TB/s where demand loads crawl at
// ~300 GB/s). One pass builds the full >0.1 key list AND the >0.98 hi-list;
// if 30 <= hcnt <= 512 the top-30 is provably inside the hi-list and wave 0
// selects alone, else full 4-wave selection over keys (no rescan needed).
// ---------------------------------------------------------------------------
__global__ __launch_bounds__(256) void peaks_kernel(const float* __restrict__ heat,
                                                    float* __restrict__ out)
{
    const int ch = blockIdx.x;              // b*17 + k
    const float* hp = heat + (size_t)ch * HW;

    __shared__ float sbuf[2][BFLT];                 // 2 x 11.25 KB strips
    __shared__ unsigned long long keys[CAP];        // 24 KB
    __shared__ unsigned long long hikeys[HICAP];    // 4 KB
    __shared__ unsigned long long sel4[4 * PPK];
    __shared__ unsigned long long sel[PPK];
    __shared__ int cnt;
    __shared__ int hcnt;

    const int tid  = threadIdx.x;
    const int lane = tid & 63;
    const int wave = tid >> 6;
    const unsigned long long ltmask = ((unsigned long long)1 << lane) - 1ull;

    if (tid == 0) { cnt = 0; hcnt = 0; }

    // ---- DMA strip helper (inlined twice below) ----
    // strip s: global rows [firstrow, lastrow] -> buffer rows (row - gbase),
    // gbase = s*16 - 1 (may be -1; buffer row 0 unused for s=0).
    auto dma_strip = [&](int s, int bb) {
        int firstrow = (s == 0) ? 0 : s * SR - 1;
        int lastrow  = (s == NSTRIP - 1) ? (HH - 1) : s * SR + SR;
        int nf4      = (lastrow - firstrow + 1) * (WW / 4);   // 680 or 720
        const float4* g  = (const float4*)(hp + firstrow * WW);
        float4*       b4 = (float4*)sbuf[bb] + ((s == 0) ? (WW / 4) : 0);
        for (int c = wave; c * 64 < nf4; c += 4) {
            int idx = c * 64 + lane;
            if (idx < nf4) async_copy16(g + idx, b4 + c * 64);
        }
    };

    dma_strip(0, 0);
    __syncthreads();   // drains DMA (vmcnt(0) before barrier) + cnt/hcnt init

    for (int s = 0; s < NSTRIP; ++s) {
        const int bb = s & 1;
        if (s < NSTRIP - 1) dma_strip(s + 1, 1 - bb);

        const float* sb   = sbuf[bb];
        const int gbase   = s * SR - 1;
        // scan 16 center rows x 40 cells = 640 cells from LDS
        for (int cell = tid; cell < SR * (WW / 4); cell += 256) {
            int ly = cell / (WW / 4);
            int cg = cell - ly * (WW / 4);
            int y  = s * SR + ly;          // global row
            int x0 = cg * 4;
            int lr = y - gbase;
            int lu = ((y > 0) ? y - 1 : 0) - gbase;
            int ld_ = ((y < HH - 1) ? y + 1 : HH - 1) - gbase;

            const float* rc = sb + lr  * WW + x0;
            const float* ru = sb + lu  * WW + x0;
            const float* rd = sb + ld_ * WW + x0;

            float4 vc = *(const float4*)rc;
            float4 vu = *(const float4*)ru;
            float4 vd = *(const float4*)rd;
            int offL = (x0 > 0) ? -1 : 0;
            int offR = (x0 + 4 < WW) ? 4 : 3;
            float lc  = rc[offL], lu_ = ru[offL], ldd = rd[offL];
            float rcx = rc[offR], rux = ru[offR], rdx = rd[offR];

            float mu0 = max3f(lu_, vu.x, vu.y), mu1 = max3f(vu.x, vu.y, vu.z);
            float mu2 = max3f(vu.y, vu.z, vu.w), mu3 = max3f(vu.z, vu.w, rux);
            float mc0 = max3f(lc, vc.x, vc.y),  mc1 = max3f(vc.x, vc.y, vc.z);
            float mc2 = max3f(vc.y, vc.z, vc.w), mc3 = max3f(vc.z, vc.w, rcx);
            float md0 = max3f(ldd, vd.x, vd.y), md1 = max3f(vd.x, vd.y, vd.z);
            float md2 = max3f(vd.y, vd.z, vd.w), md3 = max3f(vd.z, vd.w, rdx);

            float nm0 = max3f(mu0, mc0, md0);
            float nm1 = max3f(mu1, mc1, md1);
            float nm2 = max3f(mu2, mc2, md2);
            float nm3 = max3f(mu3, mc3, md3);

            bool pk0 = (vc.x == nm0) && (vc.x > 0.1f);
            bool pk1 = (vc.y == nm1) && (vc.y > 0.1f);
            bool pk2 = (vc.z == nm2) && (vc.z > 0.1f);
            bool pk3 = (vc.w == nm3) && (vc.w > 0.1f);

            int idx0 = y * WW + x0;
            unsigned long long key0 = ((unsigned long long)__float_as_uint(vc.x) << 32) | (unsigned long long)(0xFFFFFFFFu - (unsigned)(idx0 + 0));
            unsigned long long key1 = ((unsigned long long)__float_as_uint(vc.y) << 32) | (unsigned long long)(0xFFFFFFFFu - (unsigned)(idx0 + 1));
            unsigned long long key2 = ((unsigned long long)__float_as_uint(vc.z) << 32) | (unsigned long long)(0xFFFFFFFFu - (unsigned)(idx0 + 2));
            unsigned long long key3 = ((unsigned long long)__float_as_uint(vc.w) << 32) | (unsigned long long)(0xFFFFFFFFu - (unsigned)(idx0 + 3));

            // full-list append
            {
                unsigned long long b0 = __ballot(pk0);
                unsigned long long b1 = __ballot(pk1);
                unsigned long long b2 = __ballot(pk2);
                unsigned long long b3 = __ballot(pk3);
                int c0 = __popcll(b0), c1 = __popcll(b1), c2 = __popcll(b2), c3 = __popcll(b3);
                int tot = c0 + c1 + c2 + c3;
                int base = 0;
                if (lane == 0 && tot > 0) base = atomicAdd(&cnt, tot);
                base = __shfl(base, 0);
                if (pk0) { int sl = base + __popcll(b0 & ltmask); if (sl < CAP) keys[sl] = key0; }
                if (pk1) { int sl = base + c0 + __popcll(b1 & ltmask); if (sl < CAP) keys[sl] = key1; }
                if (pk2) { int sl = base + c0 + c1 + __popcll(b2 & ltmask); if (sl < CAP) keys[sl] = key2; }
                if (pk3) { int sl = base + c0 + c1 + c2 + __popcll(b3 & ltmask); if (sl < CAP) keys[sl] = key3; }
            }
            // hi-list append
            {
                bool h0 = pk0 && (vc.x > HITHR);
                bool h1 = pk1 && (vc.y > HITHR);
                bool h2 = pk2 && (vc.z > HITHR);
                bool h3 = pk3 && (vc.w > HITHR);
                unsigned long long b0 = __ballot(h0);
                unsigned long long b1 = __ballot(h1);
                unsigned long long b2 = __ballot(h2);
                unsigned long long b3 = __ballot(h3);
                int c0 = __popcll(b0), c1 = __popcll(b1), c2 = __popcll(b2), c3 = __popcll(b3);
                int tot = c0 + c1 + c2 + c3;
                if (tot > 0) {
                    int base = 0;
                    if (lane == 0) base = atomicAdd(&hcnt, tot);
                    base = __shfl(base, 0);
                    if (h0) { int sl = base + __popcll(b0 & ltmask); if (sl < HICAP) hikeys[sl] = key0; }
                    if (h1) { int sl = base + c0 + __popcll(b1 & ltmask); if (sl < HICAP) hikeys[sl] = key1; }
                    if (h2) { int sl = base + c0 + c1 + __popcll(b2 & ltmask); if (sl < HICAP) hikeys[sl] = key2; }
                    if (h3) { int sl = base + c0 + c1 + c2 + __popcll(b3 & ltmask); if (sl < HICAP) hikeys[sl] = key3; }
                }
            }
        }
        __syncthreads();   // strip scanned; DMA into other buffer drained
    }

    const int hn = hcnt;
    if (hn >= PPK && hn <= HICAP) {
        // ---- FAST PATH: wave 0 selects top-30 from <=512 hi keys ----
        if (wave == 0) {
            unsigned long long k[8];
            #pragma unroll
            for (int i = 0; i < 8; ++i) {
                int p = lane + i * 64;
                k[i] = (p < hn) ? hikeys[p] : 0ull;
            }
            for (int r = 0; r < PPK; ++r) {
                unsigned long long best = 0ull;
                #pragma unroll
                for (int i = 0; i < 8; ++i) best = umax64(best, k[i]);
                #pragma unroll
                for (int off = 1; off < 64; off <<= 1)
                    best = umax64(best, (unsigned long long)__shfl_xor((long long)best, off));
                if (best != 0ull) {
                    #pragma unroll
                    for (int i = 0; i < 8; ++i)
                        if (k[i] == best) k[i] = 0ull;     // keys unique when nonzero
                }
                if (lane == 0) sel[r] = best;
            }
        }
    } else {
        // ---- FALLBACK: 4-wave selection over the full key list ----
        const int n = (cnt < CAP) ? cnt : CAP;
        unsigned long long k[12];                     // 4 waves x 768 keys
        {
            int base0 = wave * 768 + lane;
            #pragma unroll
            for (int i = 0; i < 12; ++i) {
                int p = base0 + i * 64;
                k[i] = (p < n) ? keys[p] : 0ull;
            }
        }
        for (int r = 0; r < PPK; ++r) {
            unsigned long long best = 0ull;
            #pragma unroll
            for (int i = 0; i < 12; ++i) best = umax64(best, k[i]);
            #pragma unroll
            for (int off = 1; off < 64; off <<= 1)
                best = umax64(best, (unsigned long long)__shfl_xor((long long)best, off));
            if (best != 0ull) {
                #pragma unroll
                for (int i = 0; i < 12; ++i)
                    if (k[i] == best) k[i] = 0ull;
            }
            if (lane == 0) sel4[wave * PPK + r] = best;
        }
        __syncthreads();
        if (wave == 0) {
            unsigned long long m0 = (lane < 4 * PPK) ? sel4[lane] : 0ull;
            unsigned long long m1 = (lane + 64 < 4 * PPK) ? sel4[lane + 64] : 0ull;
            for (int r = 0; r < PPK; ++r) {
                unsigned long long best = umax64(m0, m1);
                #pragma unroll
                for (int off = 1; off < 64; off <<= 1)
                    best = umax64(best, (unsigned long long)__shfl_xor((long long)best, off));
                if (best != 0ull) {
                    if (m0 == best) m0 = 0ull;
                    else if (m1 == best) m1 = 0ull;
                }
                if (lane == 0) sel[r] = best;
            }
        }
    }
    __syncthreads();

    // ---- emit peaks with subpixel refinement (bit-identical to validated) ----
    if (tid < PPK) {
        unsigned long long g = sel[tid];
        float px = 0.0f, py = 0.0f, sc = 0.0f;
        if (g != 0ull) {
            float v = __uint_as_float((unsigned int)(g >> 32));
            int idx = (int)(0xFFFFFFFFu - (unsigned int)(g & 0xFFFFFFFFull));
            int y = idx / WW;
            int x = idx - y * WW;
            float dx = 0.0f, dy = 0.0f;
            if (x > 0 && x < WW - 1 && y > 0 && y < HH - 1) {
                float r_ = hp[y * WW + x + 1];
                float l_ = hp[y * WW + x - 1];
                float dn = hp[(y + 1) * WW + x];
                float up = hp[(y - 1) * WW + x];
                float dx_raw = 0.5f * (r_ - l_);
                float dy_raw = 0.5f * (dn - up);
                float dxx = __fsub_rn(__fadd_rn(r_, l_), 2.0f * v);
                float dyy = __fsub_rn(__fadd_rn(dn, up), 2.0f * v);
                dx = (fabsf(dxx) > 1e-6f) ? (dx_raw / (-dxx)) : dx_raw;
                dy = (fabsf(dyy) > 1e-6f) ? (dy_raw / (-dyy)) : dy_raw;
            }
            px = __fadd_rn((float)x, dx);
            py = __fadd_rn((float)y, dy);
            sc = v;
        }
        float* o = out + ((size_t)ch * PPK + tid) * 3;
        o[0] = px;
        o[1] = py;
        o[2] = sc;
    }
}

// ---------------------------------------------------------------------------
// Kernel 2: PAF connection scoring — UNCHANGED from validated round 5.
// Double-buffered quarter-plane pipeline with async global->LDS DMA.
// ---------------------------------------------------------------------------
__global__ __launch_bounds__(512, 4) void conn_kernel(const float* __restrict__ paf,
                                                      const float* __restrict__ peaks,
                                                      float* __restrict__ conn)
{
    const int bl = blockIdx.x;        // b*19 + l
    const int b  = bl / LL;
    const int l  = bl - b * LL;

    __shared__ float buf[2][QCNT];    // 2 x 25.6 KB
    __shared__ float As[PPK * 3];
    __shared__ float Bs[PPK * 3];

    const int tid  = threadIdx.x;
    const int lane = tid & 63;
    const int wave = tid >> 6;
    {
        const float* pa = peaks + (((size_t)b * KJ) + d_ska[l]) * (PPK * 3);
        const float* pb = peaks + (((size_t)b * KJ) + d_skb[l]) * (PPK * 3);
        if (tid < PPK * 3)            As[tid] = pa[tid];
        else if (tid < 2 * PPK * 3)   Bs[tid - PPK * 3] = pb[tid - PPK * 3];
    }

    const float*  src  = paf + (((size_t)b * (2 * LL)) + 2 * l) * HW;  // pafx; pafy = +HW
    const float4* src4 = (const float4*)src;

    // ---- kick off DMA of quarter 0 (pafx rows 0-39) into buf[0] ----
    {
        float4* b4 = (float4*)buf[0];
        #pragma unroll
        for (int c = 0; c < 3; ++c)
            async_copy16(src4 + c * 512 + tid, b4 + c * 512 + wave * 64);
        if (wave == 0)
            async_copy16(src4 + 1536 + lane, b4 + 1536);
    }
    __syncthreads();   // drains DMA (vmcnt(0) before barrier) + As/Bs stores

    // ---- per-pair precompute; everything constant-indexed -> registers ----
    const bool active = (tid < HALFP);
    const int p0 = active ? tid : (NPAIR - 1);
    const int p1 = active ? (tid + HALFP) : (NPAIR - 1);

    int   lin[2][SS];
    float accv[2][SS];
    float vxp[2], vyp[2], sap[2], sbp[2];

    #pragma unroll
    for (int q = 0; q < 2; ++q) {
        int p = (q == 0) ? p0 : p1;
        int i = p / PPK;
        int j = p - i * PPK;
        float ax = As[i * 3 + 0], ay = As[i * 3 + 1], sa = As[i * 3 + 2];
        float bx = Bs[j * 3 + 0], by = Bs[j * 3 + 1], sb = Bs[j * 3 + 2];
        float dxl = __fsub_rn(bx, ax);
        float dyl = __fsub_rn(by, ay);
        float nsq = __fadd_rn(__fmul_rn(dxl, dxl), __fmul_rn(dyl, dyl));
        float nrm = __fadd_rn(sqrtf(nsq), 1e-8f);
        vxp[q] = dxl / nrm;
        vyp[q] = dyl / nrm;
        sap[q] = sa;
        sbp[q] = sb;
        #pragma unroll
        for (int s = 0; s < SS; ++s) {
            float t  = d_ts[s];
            float xs = __fadd_rn(ax, __fmul_rn(t, dxl));
            float ys = __fadd_rn(ay, __fmul_rn(t, dyl));
            float rx = rintf(xs);               // round half to even, matches jnp.round
            float ry = rintf(ys);
            rx = fminf(fmaxf(rx, 0.0f), (float)(WW - 1));
            ry = fminf(fmaxf(ry, 0.0f), (float)(HH - 1));
            lin[q][s] = (int)ry * WW + (int)rx;  // in [0, HW)
        }
    }

    // ---- 8-quarter pipeline: DMA next while gathering current ----
    for (int qq = 0; qq < 8; ++qq) {
        const int cur = qq & 1;
        if (qq < 7) {
            const int nq = qq + 1;
            const float4* s4 = (const float4*)(src + (size_t)(nq >> 2) * HW + (nq & 3) * QCNT);
            float4* b4 = (float4*)buf[1 - cur];
            #pragma unroll
            for (int c = 0; c < 3; ++c)
                async_copy16(s4 + c * 512 + tid, b4 + c * 512 + wave * 64);
            if (wave == 0)
                async_copy16(s4 + 1536 + lane, b4 + 1536);
        }
        // gather current quarter from LDS (constant-indexed, fully unrolled)
        const int comp = qq >> 2;              // 0 = pafx, 1 = pafy
        const int lo   = (qq & 3) * QCNT;
        #pragma unroll
        for (int q = 0; q < 2; ++q) {
            #pragma unroll
            for (int s = 0; s < SS; ++s) {
                int lrel = lin[q][s] - lo;
                if ((unsigned)lrel < (unsigned)QCNT) {
                    float v = buf[cur][lrel];
                    if (comp == 0) accv[q][s] = __fmul_rn(v, vxp[q]);
                    else           accv[q][s] = __fadd_rn(accv[q][s], __fmul_rn(v, vyp[q]));
                }
            }
        }
        __syncthreads();   // drains gathers of buf[cur] AND the DMA into buf[1-cur]
    }

    // ---- fold + emit ----
    if (active) {
        #pragma unroll
        for (int q = 0; q < 2; ++q) {
            int p = (q == 0) ? p0 : p1;
            int cntc = 0;
            #pragma unroll
            for (int s = 0; s < SS; ++s)
                if (accv[q][s] > 0.05f) ++cntc;
            float s01 = __fadd_rn(accv[q][0], accv[q][1]);
            float s23 = __fadd_rn(accv[q][2], accv[q][3]);
            float s45 = __fadd_rn(accv[q][4], accv[q][5]);
            float s67 = __fadd_rn(accv[q][6], accv[q][7]);
            float sum = __fadd_rn(__fadd_rn(s01, s23), __fadd_rn(s45, s67));
            sum = __fadd_rn(sum, accv[q][8]);
            sum = __fadd_rn(sum, accv[q][9]);
            float mean = sum / 10.0f;
            bool va = sap[q] > 0.1f;
            bool vb = sbp[q] > 0.1f;
            bool cond = (mean > 0.0f) && (cntc >= 9) && va && vb;  // ratio>0.8 <=> cnt>=9
            float val = 0.0f;
            if (cond) val = __fadd_rn(mean, __fmul_rn(0.5f, __fadd_rn(sap[q], sbp[q])));
            conn[(size_t)bl * NPAIR + p] = val;
        }
    }
}

extern "C" void kernel_launch(void* const* d_in, const int* in_sizes, int n_in,
                              void* d_out, int out_size, void* d_ws, size_t ws_size,
                              hipStream_t stream)
{
    const float* heat = (const float*)d_in[0];   // [32,17,160,160]
    const float* paf  = (const float*)d_in[1];   // [32,38,160,160]
    float* out = (float*)d_out;

    float* peaks_out = out;                                   // 32*17*30*3 = 48960
    float* conn_out  = out + (size_t)BATCH * KJ * PPK * 3;    // 32*19*30*30 = 547200

    hipLaunchKernelGGL(peaks_kernel, dim3(BATCH * KJ), dim3(256), 0, stream,
                       heat, peaks_out);
    hipLaunchKernelGGL(conn_kernel, dim3(BATCH * LL), dim3(512), 0, stream,
                       paf, peaks_out, conn_out);
}

// Round 9
// 269.025 us; speedup vs baseline: 1.1376x; 1.0637x over previous
//
#include <hip/hip_runtime.h>
#include <cstdint>
#include <cstddef>
#include <cfloat>

// Problem constants (match reference)
static constexpr int BATCH = 32;
static constexpr int KJ    = 17;   // heat channels (joints)
static constexpr int LL    = 19;   // limbs
static constexpr int HH    = 160;
static constexpr int WW    = 160;
static constexpr int PPK   = 30;   // top-k peaks
static constexpr int SS    = 10;   // samples along limb
static constexpr int HW    = HH * WW;
static constexpr int CGW   = WW / 4;        // 40 float4 cells per row
static constexpr int CAP   = 4096;          // full candidate capacity (fallback)
static constexpr int NPAIR = PPK * PPK;     // 900
static constexpr int HALFP = NPAIR / 2;     // 450 active threads in conn
#define HITHR 0.98f

// split-peaks workspace
static constexpr int NSTR   = 4;            // strips per channel
static constexpr int SROWS  = HH / NSTR;    // 40 rows
static constexpr int SHICAP = 192;          // hi keys per strip (E~14, +~45 sigma)
static constexpr int NCH    = BATCH * KJ;   // 544
static constexpr size_t WS_KEYS_BYTES = (size_t)NCH * NSTR * SHICAP * 8;
static constexpr size_t WS_CNT_BYTES  = (size_t)NCH * NSTR * 4;
static constexpr size_t WS_NEED = WS_KEYS_BYTES + WS_CNT_BYTES;

// conn quarter-plane staging
static constexpr int QROWS = 40;
static constexpr int QCNT  = QROWS * WW;    // 6400 floats = 25.6 KB
static constexpr int QF4   = QCNT / 4;

__constant__ int d_ska[LL] = {15,13,16,14,11,5,6,5,5,6,7,8,1,0,0,1,2,3,4};
__constant__ int d_skb[LL] = {13,11,14,12,12,11,12,6,7,8,9,10,2,1,2,3,4,5,6};
__constant__ float d_ts[SS] = {
    0.0f,
    (float)(1.0/9.0), (float)(2.0/9.0), (float)(3.0/9.0),
    (float)(4.0/9.0), (float)(5.0/9.0), (float)(6.0/9.0),
    (float)(7.0/9.0), (float)(8.0/9.0),
    1.0f
};

__device__ __forceinline__ float max3f(float a, float b, float c) {
    return fmaxf(fmaxf(a, b), c);
}
__device__ __forceinline__ unsigned long long umax64(unsigned long long a, unsigned long long b) {
    return a > b ? a : b;
}
__device__ __forceinline__ void async_copy16(const float4* gsrc_lane, float4* lds_wave_base) {
    __builtin_amdgcn_global_load_lds(
        (const __attribute__((address_space(1))) void*)gsrc_lane,
        (__attribute__((address_space(3))) void*)lds_wave_base,
        16, 0, 0);
}

// ---------------------------------------------------------------------------
// K1: hi-candidate strip scan. One block per (ch,strip); 256 threads.
// Tests ONLY v > 0.98 local maxima (wave-uniform skip when no lane has a
// >0.98 center). Appends keys to a <=192-entry LDS list, dumps to ws.
// No selection work at all — this dispatch isolates pure scan throughput.
// ---------------------------------------------------------------------------
__global__ __launch_bounds__(256) void peaks_scan_hi(const float* __restrict__ heat,
                                                     unsigned long long* __restrict__ wsk,
                                                     int* __restrict__ wsc)
{
    const int blk   = blockIdx.x;           // ch*4 + strip
    const int ch    = blk >> 2;
    const int strip = blk & 3;
    const int y0    = strip * SROWS;
    const float* hp = heat + (size_t)ch * HW;

    __shared__ unsigned long long hik[SHICAP];
    __shared__ int hcnt;

    const int tid  = threadIdx.x;
    const int lane = tid & 63;
    const unsigned long long ltmask = ((unsigned long long)1 << lane) - 1ull;

    if (tid == 0) hcnt = 0;
    __syncthreads();

    for (int cell = tid; cell < SROWS * CGW; cell += 256) {
        int ly = cell / CGW;
        int cg = cell - ly * CGW;
        int y  = y0 + ly;
        int x0 = cg * 4;
        const float* rc = hp + y * WW + x0;
        float4 vc = *(const float4*)rc;

        bool h_any = (vc.x > HITHR) || (vc.y > HITHR) || (vc.z > HITHR) || (vc.w > HITHR);
        bool h0 = false, h1 = false, h2 = false, h3 = false;
        if (__any(h_any ? 1 : 0)) {          // wave-uniform; ~43% of iterations
            int yu = (y > 0) ? y - 1 : 0;
            int yd = (y < HH - 1) ? y + 1 : HH - 1;
            const float* ru = hp + yu * WW + x0;
            const float* rd = hp + yd * WW + x0;
            float4 vu = *(const float4*)ru;
            float4 vd = *(const float4*)rd;
            int offL = (x0 > 0) ? -1 : 0;
            int offR = (x0 + 4 < WW) ? 4 : 3;
            float lc  = rc[offL], lu  = ru[offL], ld  = rd[offL];
            float rcx = rc[offR], rux = ru[offR], rdx = rd[offR];

            float mu0 = max3f(lu, vu.x, vu.y), mu1 = max3f(vu.x, vu.y, vu.z);
            float mu2 = max3f(vu.y, vu.z, vu.w), mu3 = max3f(vu.z, vu.w, rux);
            float mc0 = max3f(lc, vc.x, vc.y), mc1 = max3f(vc.x, vc.y, vc.z);
            float mc2 = max3f(vc.y, vc.z, vc.w), mc3 = max3f(vc.z, vc.w, rcx);
            float md0 = max3f(ld, vd.x, vd.y), md1 = max3f(vd.x, vd.y, vd.z);
            float md2 = max3f(vd.y, vd.z, vd.w), md3 = max3f(vd.z, vd.w, rdx);

            float nm0 = max3f(mu0, mc0, md0);
            float nm1 = max3f(mu1, mc1, md1);
            float nm2 = max3f(mu2, mc2, md2);
            float nm3 = max3f(mu3, mc3, md3);

            h0 = (vc.x == nm0) && (vc.x > HITHR);
            h1 = (vc.y == nm1) && (vc.y > HITHR);
            h2 = (vc.z == nm2) && (vc.z > HITHR);
            h3 = (vc.w == nm3) && (vc.w > HITHR);
        }
        unsigned long long b0 = __ballot(h0);
        unsigned long long b1 = __ballot(h1);
        unsigned long long b2 = __ballot(h2);
        unsigned long long b3 = __ballot(h3);
        int c0 = __popcll(b0), c1 = __popcll(b1), c2 = __popcll(b2), c3 = __popcll(b3);
        int tot = c0 + c1 + c2 + c3;
        if (tot == 0) continue;
        int base = 0;
        if (lane == 0) base = atomicAdd(&hcnt, tot);
        base = __shfl(base, 0);

        int idx0 = y * WW + x0;
        if (h0) { int s = base + __popcll(b0 & ltmask); if (s < SHICAP)
            hik[s] = ((unsigned long long)__float_as_uint(vc.x) << 32) | (unsigned long long)(0xFFFFFFFFu - (unsigned)(idx0 + 0)); }
        if (h1) { int s = base + c0 + __popcll(b1 & ltmask); if (s < SHICAP)
            hik[s] = ((unsigned long long)__float_as_uint(vc.y) << 32) | (unsigned long long)(0xFFFFFFFFu - (unsigned)(idx0 + 1)); }
        if (h2) { int s = base + c0 + c1 + __popcll(b2 & ltmask); if (s < SHICAP)
            hik[s] = ((unsigned long long)__float_as_uint(vc.z) << 32) | (unsigned long long)(0xFFFFFFFFu - (unsigned)(idx0 + 2)); }
        if (h3) { int s = base + c0 + c1 + c2 + __popcll(b3 & ltmask); if (s < SHICAP)
            hik[s] = ((unsigned long long)__float_as_uint(vc.w) << 32) | (unsigned long long)(0xFFFFFFFFu - (unsigned)(idx0 + 3)); }
    }
    __syncthreads();

    if (tid == 0) wsc[blk] = hcnt;                       // raw count (overflow detectable)
    const int n = (hcnt < SHICAP) ? hcnt : SHICAP;
    for (int i = tid; i < n; i += 256)
        wsk[(size_t)blk * SHICAP + i] = hik[i];
}

// ---------------------------------------------------------------------------
// K2: selection + subpixel refine + emit. One block of 256 per channel.
// Fast path (all strip counts <=192 and total >=30): compact keys into LDS,
// rank-select WITHOUT butterflies: each thread reads all n keys (LDS
// broadcast, independent & pipelined), rank = #strictly-greater; rank<30
// writes sel[rank]. Exact: keys unique; >=30 keys above 0.98 => top-30 is
// entirely above 0.98 (r6-validated argument).
// Fallback (rare, exactness): full >0.1 rescan + butterfly selection.
// ---------------------------------------------------------------------------
__global__ __launch_bounds__(256, 4) void peaks_select(const float* __restrict__ heat,
                                                       const unsigned long long* __restrict__ wsk,
                                                       const int* __restrict__ wsc,
                                                       float* __restrict__ out)
{
    const int ch = blockIdx.x;
    const float* hp = heat + (size_t)ch * HW;

    __shared__ unsigned long long keys[CAP];            // 32 KB (fast path uses <=768)
    __shared__ unsigned long long sel4[4 * PPK];
    __shared__ unsigned long long sel[PPK];
    __shared__ int cnt;

    const int tid  = threadIdx.x;
    const int lane = tid & 63;
    const int wave = tid >> 6;
    const unsigned long long ltmask = ((unsigned long long)1 << lane) - 1ull;

    const int c0 = wsc[ch * 4 + 0];
    const int c1 = wsc[ch * 4 + 1];
    const int c2 = wsc[ch * 4 + 2];
    const int c3 = wsc[ch * 4 + 3];
    const bool ok = (c0 <= SHICAP) && (c1 <= SHICAP) && (c2 <= SHICAP) && (c3 <= SHICAP);
    const int n = c0 + c1 + c2 + c3;

    if (tid == 0) cnt = 0;

    if (ok && n >= PPK) {
        // ---- FAST PATH ----
        const int off1 = c0, off2 = c0 + c1, off3 = c0 + c1 + c2;
        for (int i = tid; i < c0; i += 256) keys[i]        = wsk[(size_t)(ch * 4 + 0) * SHICAP + i];
        for (int i = tid; i < c1; i += 256) keys[off1 + i] = wsk[(size_t)(ch * 4 + 1) * SHICAP + i];
        for (int i = tid; i < c2; i += 256) keys[off2 + i] = wsk[(size_t)(ch * 4 + 2) * SHICAP + i];
        for (int i = tid; i < c3; i += 256) keys[off3 + i] = wsk[(size_t)(ch * 4 + 3) * SHICAP + i];
        __syncthreads();

        unsigned long long mine0 = (tid < n)       ? keys[tid]       : 0ull;
        unsigned long long mine1 = (tid + 256 < n) ? keys[tid + 256] : 0ull;
        unsigned long long mine2 = (tid + 512 < n) ? keys[tid + 512] : 0ull;
        int r0 = 0, r1 = 0, r2 = 0;
        for (int j = 0; j < n; ++j) {
            unsigned long long kj = keys[j];     // broadcast read, conflict-free
            r0 += (kj > mine0) ? 1 : 0;
            r1 += (kj > mine1) ? 1 : 0;
            r2 += (kj > mine2) ? 1 : 0;
        }
        if (tid < n       && r0 < PPK) sel[r0] = mine0;
        if (tid + 256 < n && r1 < PPK) sel[r1] = mine1;
        if (tid + 512 < n && r2 < PPK) sel[r2] = mine2;
        __syncthreads();
    } else {
        // ---- FALLBACK: full >0.1 rescan + butterfly selection (validated) ----
        __syncthreads();                       // cnt init visible
        for (int c = tid; c < HW / 4; c += 256) {
            int y  = c / CGW;
            int cg = c - y * CGW;
            int x0 = cg * 4;
            int yu = (y > 0) ? y - 1 : 0;
            int yd = (y < HH - 1) ? y + 1 : HH - 1;
            const float* rc = hp + y  * WW + x0;
            const float* ru = hp + yu * WW + x0;
            const float* rd = hp + yd * WW + x0;
            float4 vc = *(const float4*)rc;
            float4 vu = *(const float4*)ru;
            float4 vd = *(const float4*)rd;
            int offL = (x0 > 0) ? -1 : 0;
            int offR = (x0 + 4 < WW) ? 4 : 3;
            float lc  = rc[offL], lu  = ru[offL], ld  = rd[offL];
            float rcx = rc[offR], rux = ru[offR], rdx = rd[offR];

            float mu0 = max3f(lu, vu.x, vu.y), mu1 = max3f(vu.x, vu.y, vu.z);
            float mu2 = max3f(vu.y, vu.z, vu.w), mu3 = max3f(vu.z, vu.w, rux);
            float mc0 = max3f(lc, vc.x, vc.y), mc1 = max3f(vc.x, vc.y, vc.z);
            float mc2 = max3f(vc.y, vc.z, vc.w), mc3 = max3f(vc.z, vc.w, rcx);
            float md0 = max3f(ld, vd.x, vd.y), md1 = max3f(vd.x, vd.y, vd.z);
            float md2 = max3f(vd.y, vd.z, vd.w), md3 = max3f(vd.z, vd.w, rdx);

            float nm0 = max3f(mu0, mc0, md0);
            float nm1 = max3f(mu1, mc1, md1);
            float nm2 = max3f(mu2, mc2, md2);
            float nm3 = max3f(mu3, mc3, md3);

            bool pk0 = (vc.x == nm0) && (vc.x > 0.1f);
            bool pk1 = (vc.y == nm1) && (vc.y > 0.1f);
            bool pk2 = (vc.z == nm2) && (vc.z > 0.1f);
            bool pk3 = (vc.w == nm3) && (vc.w > 0.1f);

            unsigned long long b0 = __ballot(pk0);
            unsigned long long b1 = __ballot(pk1);
            unsigned long long b2 = __ballot(pk2);
            unsigned long long b3 = __ballot(pk3);
            int d0 = __popcll(b0), d1 = __popcll(b1), d2 = __popcll(b2), d3 = __popcll(b3);
            int tot = d0 + d1 + d2 + d3;
            int base = 0;
            if (lane == 0 && tot > 0) base = atomicAdd(&cnt, tot);
            base = __shfl(base, 0);

            int idx0 = y * WW + x0;
            if (pk0) { int s = base + __popcll(b0 & ltmask); if (s < CAP)
                keys[s] = ((unsigned long long)__float_as_uint(vc.x) << 32) | (unsigned long long)(0xFFFFFFFFu - (unsigned)(idx0 + 0)); }
            if (pk1) { int s = base + d0 + __popcll(b1 & ltmask); if (s < CAP)
                keys[s] = ((unsigned long long)__float_as_uint(vc.y) << 32) | (unsigned long long)(0xFFFFFFFFu - (unsigned)(idx0 + 1)); }
            if (pk2) { int s = base + d0 + d1 + __popcll(b2 & ltmask); if (s < CAP)
                keys[s] = ((unsigned long long)__float_as_uint(vc.z) << 32) | (unsigned long long)(0xFFFFFFFFu - (unsigned)(idx0 + 2)); }
            if (pk3) { int s = base + d0 + d1 + d2 + __popcll(b3 & ltmask); if (s < CAP)
                keys[s] = ((unsigned long long)__float_as_uint(vc.w) << 32) | (unsigned long long)(0xFFFFFFFFu - (unsigned)(idx0 + 3)); }
        }
        __syncthreads();

        const int m = (cnt < CAP) ? cnt : CAP;
        unsigned long long k[16];
        {
            int base0 = wave * 1024 + lane;
            #pragma unroll
            for (int i = 0; i < 16; ++i) {
                int p = base0 + i * 64;
                k[i] = (p < m) ? keys[p] : 0ull;
            }
        }
        for (int r = 0; r < PPK; ++r) {
            unsigned long long best = 0ull;
            #pragma unroll
            for (int i = 0; i < 16; ++i) best = umax64(best, k[i]);
            #pragma unroll
            for (int off = 1; off < 64; off <<= 1)
                best = umax64(best, (unsigned long long)__shfl_xor((long long)best, off));
            if (best != 0ull) {
                #pragma unroll
                for (int i = 0; i < 16; ++i)
                    if (k[i] == best) k[i] = 0ull;
            }
            if (lane == 0) sel4[wave * PPK + r] = best;
        }
        __syncthreads();
        if (wave == 0) {
            unsigned long long m0 = (lane < 4 * PPK) ? sel4[lane] : 0ull;
            unsigned long long m1 = (lane + 64 < 4 * PPK) ? sel4[lane + 64] : 0ull;
            for (int r = 0; r < PPK; ++r) {
                unsigned long long best = umax64(m0, m1);
                #pragma unroll
                for (int off = 1; off < 64; off <<= 1)
                    best = umax64(best, (unsigned long long)__shfl_xor((long long)best, off));
                if (best != 0ull) {
                    if (m0 == best) m0 = 0ull;
                    else if (m1 == best) m1 = 0ull;
                }
                if (lane == 0) sel[r] = best;
            }
        }
        __syncthreads();
    }

    // ---- emit peaks with subpixel refinement (bit-identical to validated) ----
    if (tid < PPK) {
        unsigned long long g = sel[tid];
        float px = 0.0f, py = 0.0f, sc = 0.0f;
        if (g != 0ull) {
            float v = __uint_as_float((unsigned int)(g >> 32));
            int idx = (int)(0xFFFFFFFFu - (unsigned int)(g & 0xFFFFFFFFull));
            int y = idx / WW;
            int x = idx - y * WW;
            float dx = 0.0f, dy = 0.0f;
            if (x > 0 && x < WW - 1 && y > 0 && y < HH - 1) {
                float r_ = hp[y * WW + x + 1];
                float l_ = hp[y * WW + x - 1];
                float dn = hp[(y + 1) * WW + x];
                float up = hp[(y - 1) * WW + x];
                float dx_raw = 0.5f * (r_ - l_);
                float dy_raw = 0.5f * (dn - up);
                float dxx = __fsub_rn(__fadd_rn(r_, l_), 2.0f * v);
                float dyy = __fsub_rn(__fadd_rn(dn, up), 2.0f * v);
                dx = (fabsf(dxx) > 1e-6f) ? (dx_raw / (-dxx)) : dx_raw;
                dy = (fabsf(dyy) > 1e-6f) ? (dy_raw / (-dyy)) : dy_raw;
            }
            px = __fadd_rn((float)x, dx);
            py = __fadd_rn((float)y, dy);
            sc = v;
        }
        float* o = out + ((size_t)ch * PPK + tid) * 3;
        o[0] = px;
        o[1] = py;
        o[2] = sc;
    }
}

// ---------------------------------------------------------------------------
// Fused fallback peaks kernel (r6, validated, 85 µs) — used if ws too small.
// ---------------------------------------------------------------------------
static constexpr int FHICAP = 512;
__global__ __launch_bounds__(512, 4) void peaks_fused(const float* __restrict__ heat,
                                                      float* __restrict__ out)
{
    const int ch = blockIdx.x;
    const float* hp = heat + (size_t)ch * HW;

    __shared__ unsigned long long keys[CAP];
    __shared__ unsigned long long hikeys[FHICAP];
    __shared__ unsigned long long sel8[8 * PPK];
    __shared__ unsigned long long sel[PPK];
    __shared__ int cnt;
    __shared__ int hcnt;

    const int tid  = threadIdx.x;
    const int lane = tid & 63;
    const int wave = tid >> 6;
    const unsigned long long ltmask = ((unsigned long long)1 << lane) - 1ull;

    if (tid == 0) { cnt = 0; hcnt = 0; }
    __syncthreads();

    for (int c = tid; c < HW / 4; c += 512) {
        int y  = c / CGW;
        int cg = c - y * CGW;
        int x0 = cg * 4;
        int yu = (y > 0) ? y - 1 : 0;
        int yd = (y < HH - 1) ? y + 1 : HH - 1;
        const float* rc = hp + y  * WW + x0;
        const float* ru = hp + yu * WW + x0;
        const float* rd = hp + yd * WW + x0;
        float4 vc = *(const float4*)rc;
        float4 vu = *(const float4*)ru;
        float4 vd = *(const float4*)rd;
        int offL = (x0 > 0) ? -1 : 0;
        int offR = (x0 + 4 < WW) ? 4 : 3;
        float lc  = rc[offL], lu  = ru[offL], ld  = rd[offL];
        float rcx = rc[offR], rux = ru[offR], rdx = rd[offR];
        float mu0 = max3f(lu, vu.x, vu.y), mu1 = max3f(vu.x, vu.y, vu.z);
        float mu2 = max3f(vu.y, vu.z, vu.w), mu3 = max3f(vu.z, vu.w, rux);
        float mc0 = max3f(lc, vc.x, vc.y), mc1 = max3f(vc.x, vc.y, vc.z);
        float mc2 = max3f(vc.y, vc.z, vc.w), mc3 = max3f(vc.z, vc.w, rcx);
        float md0 = max3f(ld, vd.x, vd.y), md1 = max3f(vd.x, vd.y, vd.z);
        float md2 = max3f(vd.y, vd.z, vd.w), md3 = max3f(vd.z, vd.w, rdx);
        float nm0 = max3f(mu0, mc0, md0);
        float nm1 = max3f(mu1, mc1, md1);
        float nm2 = max3f(mu2, mc2, md2);
        float nm3 = max3f(mu3, mc3, md3);
        bool pk0 = (vc.x == nm0) && (vc.x > 0.1f);
        bool pk1 = (vc.y == nm1) && (vc.y > 0.1f);
        bool pk2 = (vc.z == nm2) && (vc.z > 0.1f);
        bool pk3 = (vc.w == nm3) && (vc.w > 0.1f);
        int idx0 = y * WW + x0;
        unsigned long long key0 = ((unsigned long long)__float_as_uint(vc.x) << 32) | (unsigned long long)(0xFFFFFFFFu - (unsigned)(idx0 + 0));
        unsigned long long key1 = ((unsigned long long)__float_as_uint(vc.y) << 32) | (unsigned long long)(0xFFFFFFFFu - (unsigned)(idx0 + 1));
        unsigned long long key2 = ((unsigned long long)__float_as_uint(vc.z) << 32) | (unsigned long long)(0xFFFFFFFFu - (unsigned)(idx0 + 2));
        unsigned long long key3 = ((unsigned long long)__float_as_uint(vc.w) << 32) | (unsigned long long)(0xFFFFFFFFu - (unsigned)(idx0 + 3));
        {
            unsigned long long b0 = __ballot(pk0);
            unsigned long long b1 = __ballot(pk1);
            unsigned long long b2 = __ballot(pk2);
            unsigned long long b3 = __ballot(pk3);
            int c0 = __popcll(b0), c1 = __popcll(b1), c2 = __popcll(b2), c3 = __popcll(b3);
            int tot = c0 + c1 + c2 + c3;
            int base = 0;
            if (lane == 0 && tot > 0) base = atomicAdd(&cnt, tot);
            base = __shfl(base, 0);
            if (pk0) { int s = base + __popcll(b0 & ltmask); if (s < CAP) keys[s] = key0; }
            if (pk1) { int s = base + c0 + __popcll(b1 & ltmask); if (s < CAP) keys[s] = key1; }
            if (pk2) { int s = base + c0 + c1 + __popcll(b2 & ltmask); if (s < CAP) keys[s] = key2; }
            if (pk3) { int s = base + c0 + c1 + c2 + __popcll(b3 & ltmask); if (s < CAP) keys[s] = key3; }
        }
        {
            bool h0 = pk0 && (vc.x > HITHR);
            bool h1 = pk1 && (vc.y > HITHR);
            bool h2 = pk2 && (vc.z > HITHR);
            bool h3 = pk3 && (vc.w > HITHR);
            unsigned long long b0 = __ballot(h0);
            unsigned long long b1 = __ballot(h1);
            unsigned long long b2 = __ballot(h2);
            unsigned long long b3 = __ballot(h3);
            int c0 = __popcll(b0), c1 = __popcll(b1), c2 = __popcll(b2), c3 = __popcll(b3);
            int tot = c0 + c1 + c2 + c3;
            if (tot > 0) {
                int base = 0;
                if (lane == 0) base = atomicAdd(&hcnt, tot);
                base = __shfl(base, 0);
                if (h0) { int s = base + __popcll(b0 & ltmask); if (s < FHICAP) hikeys[s] = key0; }
                if (h1) { int s = base + c0 + __popcll(b1 & ltmask); if (s < FHICAP) hikeys[s] = key1; }
                if (h2) { int s = base + c0 + c1 + __popcll(b2 & ltmask); if (s < FHICAP) hikeys[s] = key2; }
                if (h3) { int s = base + c0 + c1 + c2 + __popcll(b3 & ltmask); if (s < FHICAP) hikeys[s] = key3; }
            }
        }
    }
    __syncthreads();

    const int hn = hcnt;
    if (hn >= PPK && hn <= FHICAP) {
        if (wave == 0) {
            unsigned long long k[8];
            #pragma unroll
            for (int i = 0; i < 8; ++i) {
                int p = lane + i * 64;
                k[i] = (p < hn) ? hikeys[p] : 0ull;
            }
            for (int r = 0; r < PPK; ++r) {
                unsigned long long best = 0ull;
                #pragma unroll
                for (int i = 0; i < 8; ++i) best = umax64(best, k[i]);
                #pragma unroll
                for (int off = 1; off < 64; off <<= 1)
                    best = umax64(best, (unsigned long long)__shfl_xor((long long)best, off));
                if (best != 0ull) {
                    #pragma unroll
                    for (int i = 0; i < 8; ++i)
                        if (k[i] == best) k[i] = 0ull;
                }
                if (lane == 0) sel[r] = best;
            }
        }
    } else {
        const int n = (cnt < CAP) ? cnt : CAP;
        unsigned long long k[8];
        {
            int base0 = wave * 512 + lane;
            #pragma unroll
            for (int i = 0; i < 8; ++i) {
                int p = base0 + i * 64;
                k[i] = (p < n) ? keys[p] : 0ull;
            }
        }
        for (int r = 0; r < PPK; ++r) {
            unsigned long long best = 0ull;
            #pragma unroll
            for (int i = 0; i < 8; ++i) best = umax64(best, k[i]);
            #pragma unroll
            for (int off = 1; off < 64; off <<= 1)
                best = umax64(best, (unsigned long long)__shfl_xor((long long)best, off));
            if (best != 0ull) {
                #pragma unroll
                for (int i = 0; i < 8; ++i)
                    if (k[i] == best) k[i] = 0ull;
            }
            if (lane == 0) sel8[wave * PPK + r] = best;
        }
        __syncthreads();
        if (wave == 0) {
            unsigned long long m[4];
            #pragma unroll
            for (int i = 0; i < 4; ++i) {
                int p = lane + i * 64;
                m[i] = (p < 8 * PPK) ? sel8[p] : 0ull;
            }
            for (int r = 0; r < PPK; ++r) {
                unsigned long long best = umax64(umax64(m[0], m[1]), umax64(m[2], m[3]));
                #pragma unroll
                for (int off = 1; off < 64; off <<= 1)
                    best = umax64(best, (unsigned long long)__shfl_xor((long long)best, off));
                if (best != 0ull) {
                    #pragma unroll
                    for (int i = 0; i < 4; ++i)
                        if (m[i] == best) m[i] = 0ull;
                }
                if (lane == 0) sel[r] = best;
            }
        }
    }
    __syncthreads();

    if (tid < PPK) {
        unsigned long long g = sel[tid];
        float px = 0.0f, py = 0.0f, sc = 0.0f;
        if (g != 0ull) {
            float v = __uint_as_float((unsigned int)(g >> 32));
            int idx = (int)(0xFFFFFFFFu - (unsigned int)(g & 0xFFFFFFFFull));
            int y = idx / WW;
            int x = idx - y * WW;
            float dx = 0.0f, dy = 0.0f;
            if (x > 0 && x < WW - 1 && y > 0 && y < HH - 1) {
                float r_ = hp[y * WW + x + 1];
                float l_ = hp[y * WW + x - 1];
                float dn = hp[(y + 1) * WW + x];
                float up = hp[(y - 1) * WW + x];
                float dx_raw = 0.5f * (r_ - l_);
                float dy_raw = 0.5f * (dn - up);
                float dxx = __fsub_rn(__fadd_rn(r_, l_), 2.0f * v);
                float dyy = __fsub_rn(__fadd_rn(dn, up), 2.0f * v);
                dx = (fabsf(dxx) > 1e-6f) ? (dx_raw / (-dxx)) : dx_raw;
                dy = (fabsf(dyy) > 1e-6f) ? (dy_raw / (-dyy)) : dy_raw;
            }
            px = __fadd_rn((float)x, dx);
            py = __fadd_rn((float)y, dy);
            sc = v;
        }
        float* o = out + ((size_t)ch * PPK + tid) * 3;
        o[0] = px;
        o[1] = py;
        o[2] = sc;
    }
}

// ---------------------------------------------------------------------------
// Kernel 2: PAF connection scoring — UNCHANGED from validated round 5.
// ---------------------------------------------------------------------------
__global__ __launch_bounds__(512, 4) void conn_kernel(const float* __restrict__ paf,
                                                      const float* __restrict__ peaks,
                                                      float* __restrict__ conn)
{
    const int bl = blockIdx.x;
    const int b  = bl / LL;
    const int l  = bl - b * LL;

    __shared__ float buf[2][QCNT];
    __shared__ float As[PPK * 3];
    __shared__ float Bs[PPK * 3];

    const int tid  = threadIdx.x;
    const int lane = tid & 63;
    const int wave = tid >> 6;
    {
        const float* pa = peaks + (((size_t)b * KJ) + d_ska[l]) * (PPK * 3);
        const float* pb = peaks + (((size_t)b * KJ) + d_skb[l]) * (PPK * 3);
        if (tid < PPK * 3)            As[tid] = pa[tid];
        else if (tid < 2 * PPK * 3)   Bs[tid - PPK * 3] = pb[tid - PPK * 3];
    }

    const float*  src  = paf + (((size_t)b * (2 * LL)) + 2 * l) * HW;
    const float4* src4 = (const float4*)src;

    {
        float4* b4 = (float4*)buf[0];
        #pragma unroll
        for (int c = 0; c < 3; ++c)
            async_copy16(src4 + c * 512 + tid, b4 + c * 512 + wave * 64);
        if (wave == 0)
            async_copy16(src4 + 1536 + lane, b4 + 1536);
    }
    __syncthreads();

    const bool active = (tid < HALFP);
    const int p0 = active ? tid : (NPAIR - 1);
    const int p1 = active ? (tid + HALFP) : (NPAIR - 1);

    int   lin[2][SS];
    float accv[2][SS];
    float vxp[2], vyp[2], sap[2], sbp[2];

    #pragma unroll
    for (int q = 0; q < 2; ++q) {
        int p = (q == 0) ? p0 : p1;
        int i = p / PPK;
        int j = p - i * PPK;
        float ax = As[i * 3 + 0], ay = As[i * 3 + 1], sa = As[i * 3 + 2];
        float bx = Bs[j * 3 + 0], by = Bs[j * 3 + 1], sb = Bs[j * 3 + 2];
        float dxl = __fsub_rn(bx, ax);
        float dyl = __fsub_rn(by, ay);
        float nsq = __fadd_rn(__fmul_rn(dxl, dxl), __fmul_rn(dyl, dyl));
        float nrm = __fadd_rn(sqrtf(nsq), 1e-8f);
        vxp[q] = dxl / nrm;
        vyp[q] = dyl / nrm;
        sap[q] = sa;
        sbp[q] = sb;
        #pragma unroll
        for (int s = 0; s < SS; ++s) {
            float t  = d_ts[s];
            float xs = __fadd_rn(ax, __fmul_rn(t, dxl));
            float ys = __fadd_rn(ay, __fmul_rn(t, dyl));
            float rx = rintf(xs);
            float ry = rintf(ys);
            rx = fminf(fmaxf(rx, 0.0f), (float)(WW - 1));
            ry = fminf(fmaxf(ry, 0.0f), (float)(HH - 1));
            lin[q][s] = (int)ry * WW + (int)rx;
        }
    }

    for (int qq = 0; qq < 8; ++qq) {
        const int cur = qq & 1;
        if (qq < 7) {
            const int nq = qq + 1;
            const float4* s4 = (const float4*)(src + (size_t)(nq >> 2) * HW + (nq & 3) * QCNT);
            float4* b4 = (float4*)buf[1 - cur];
            #pragma unroll
            for (int c = 0; c < 3; ++c)
                async_copy16(s4 + c * 512 + tid, b4 + c * 512 + wave * 64);
            if (wave == 0)
                async_copy16(s4 + 1536 + lane, b4 + 1536);
        }
        const int comp = qq >> 2;
        const int lo   = (qq & 3) * QCNT;
        #pragma unroll
        for (int q = 0; q < 2; ++q) {
            #pragma unroll
            for (int s = 0; s < SS; ++s) {
                int lrel = lin[q][s] - lo;
                if ((unsigned)lrel < (unsigned)QCNT) {
                    float v = buf[cur][lrel];
                    if (comp == 0) accv[q][s] = __fmul_rn(v, vxp[q]);
                    else           accv[q][s] = __fadd_rn(accv[q][s], __fmul_rn(v, vyp[q]));
                }
            }
        }
        __syncthreads();
    }

    if (active) {
        #pragma unroll
        for (int q = 0; q < 2; ++q) {
            int p = (q == 0) ? p0 : p1;
            int cntc = 0;
            #pragma unroll
            for (int s = 0; s < SS; ++s)
                if (accv[q][s] > 0.05f) ++cntc;
            float s01 = __fadd_rn(accv[q][0], accv[q][1]);
            float s23 = __fadd_rn(accv[q][2], accv[q][3]);
            float s45 = __fadd_rn(accv[q][4], accv[q][5]);
            float s67 = __fadd_rn(accv[q][6], accv[q][7]);
            float sum = __fadd_rn(__fadd_rn(s01, s23), __fadd_rn(s45, s67));
            sum = __fadd_rn(sum, accv[q][8]);
            sum = __fadd_rn(sum, accv[q][9]);
            float mean = sum / 10.0f;
            bool va = sap[q] > 0.1f;
            bool vb = sbp[q] > 0.1f;
            bool cond = (mean > 0.0f) && (cntc >= 9) && va && vb;
            float val = 0.0f;
            if (cond) val = __fadd_rn(mean, __fmul_rn(0.5f, __fadd_rn(sap[q], sbp[q])));
            conn[(size_t)bl * NPAIR + p] = val;
        }
    }
}

extern "C" void kernel_launch(void* const* d_in, const int* in_sizes, int n_in,
                              void* d_out, int out_size, void* d_ws, size_t ws_size,
                              hipStream_t stream)
{
    const float* heat = (const float*)d_in[0];   // [32,17,160,160]
    const float* paf  = (const float*)d_in[1];   // [32,38,160,160]
    float* out = (float*)d_out;

    float* peaks_out = out;                                   // 48960
    float* conn_out  = out + (size_t)BATCH * KJ * PPK * 3;    // 547200

    if (ws_size >= WS_NEED) {
        unsigned long long* wsk = (unsigned long long*)d_ws;
        int* wsc = (int*)((char*)d_ws + WS_KEYS_BYTES);
        hipLaunchKernelGGL(peaks_scan_hi, dim3(NCH * NSTR), dim3(256), 0, stream,
                           heat, wsk, wsc);
        hipLaunchKernelGGL(peaks_select, dim3(NCH), dim3(256), 0, stream,
                           heat, wsk, wsc, peaks_out);
    } else {
        hipLaunchKernelGGL(peaks_fused, dim3(NCH), dim3(512), 0, stream,
                           heat, peaks_out);
    }
    hipLaunchKernelGGL(conn_kernel, dim3(BATCH * LL), dim3(512), 0, stream,
                       paf, peaks_out, conn_out);
}